// Round 1
// baseline (3232.352 us; speedup 1.0000x reference)
//
#include <hip/hip_runtime.h>
#include <hip/hip_bf16.h>

// Problem constants
#define BATCH 4
#define CCH   256     // channels
#define NPOS  4096    // H*W
#define NGRP  8
#define CPG   32      // channels per group

// ---------------------------------------------------------------------------
// GroupNorm: one block per (b,g). mean/var over CPG*NPOS = 131072 elements.
// ---------------------------------------------------------------------------
__global__ __launch_bounds__(256) void gn_kernel(
    const float* __restrict__ x, const float* __restrict__ gamma,
    const float* __restrict__ beta, float* __restrict__ xn)
{
    const int bg = blockIdx.x;            // b*NGRP + g
    const int g  = bg & (NGRP - 1);
    const size_t base = (size_t)bg * CPG * NPOS;
    const int t = threadIdx.x;
    const int M4 = CPG * NPOS / 4;        // 32768 float4s

    const float4* x4 = (const float4*)(x + base);
    float s = 0.f, s2 = 0.f;
    for (int i = t; i < M4; i += 256) {
        float4 v = x4[i];
        s  += v.x + v.y + v.z + v.w;
        s2 += v.x*v.x + v.y*v.y + v.z*v.z + v.w*v.w;
    }
    // wave reduce (64 lanes)
    for (int off = 32; off; off >>= 1) {
        s  += __shfl_down(s,  off);
        s2 += __shfl_down(s2, off);
    }
    __shared__ float rs[4], rs2[4];
    __shared__ float mu_s, rstd_s;
    const int wid = t >> 6;
    if ((t & 63) == 0) { rs[wid] = s; rs2[wid] = s2; }
    __syncthreads();
    if (t == 0) {
        float S  = rs[0] + rs[1] + rs[2] + rs[3];
        float S2 = rs2[0] + rs2[1] + rs2[2] + rs2[3];
        const float inv = 1.0f / (float)(CPG * NPOS);
        float mu  = S * inv;
        float var = S2 * inv - mu * mu;
        mu_s = mu;
        rstd_s = rsqrtf(var + 1e-5f);
    }
    __syncthreads();
    const float mu = mu_s, rstd = rstd_s;
    float4* o4 = (float4*)(xn + base);
    for (int i = t; i < M4; i += 256) {
        const int c = g * CPG + (i >> 10);   // N/4 = 1024 float4 per channel
        const float ga = gamma[c] * rstd;
        const float be = beta[c] - mu * ga;
        float4 v = x4[i];
        v.x = v.x * ga + be;
        v.y = v.y * ga + be;
        v.z = v.z * ga + be;
        v.w = v.w * ga + be;
        o4[i] = v;
    }
}

// ---------------------------------------------------------------------------
// GEMM: Y[b,o,n] = sum_c W[o,c] * X[b,c,n] + bias[o] (+ resid[b,o,n])
// 64x64 tile, 256 threads, 4x4 microtile, K=256.
// grid: (NPOS/64, CCH/64, BATCH)
// ---------------------------------------------------------------------------
__global__ __launch_bounds__(256) void gemm256(
    const float* __restrict__ W, const float* __restrict__ X,
    const float* __restrict__ bias, const float* __restrict__ resid,
    float* __restrict__ Y)
{
    const int b  = blockIdx.z;
    const int n0 = blockIdx.x * 64;
    const int o0 = blockIdx.y * 64;
    const int t  = threadIdx.x;
    const int tx = t & 15, ty = t >> 4;

    __shared__ float Ws[16][68];   // Ws[k][o]  (pad 68 -> 2-way max on write)
    __shared__ float Xs[16][64];   // Xs[k][n]

    float acc[4][4];
    #pragma unroll
    for (int i = 0; i < 4; i++)
        #pragma unroll
        for (int j = 0; j < 4; j++) acc[i][j] = 0.f;

    const float* Xb = X + (size_t)b * CCH * NPOS;

    for (int kk = 0; kk < CCH; kk += 16) {
        {   // W tile: W[o0+r][kk+c] -> Ws[c][r]
            const int c = t & 15;
            const int r = t >> 4;
            #pragma unroll
            for (int i = 0; i < 4; i++)
                Ws[c][r + i*16] = W[(size_t)(o0 + r + i*16) * CCH + kk + c];
        }
        {   // X tile: X[kk+r][n0+c] -> Xs[r][c]
            const int cc = t & 63;
            const int rr = t >> 6;
            #pragma unroll
            for (int i = 0; i < 4; i++)
                Xs[rr + i*4][cc] = Xb[(size_t)(kk + rr + i*4) * NPOS + n0 + cc];
        }
        __syncthreads();
        #pragma unroll
        for (int k = 0; k < 16; k++) {
            float a[4], bb[4];
            #pragma unroll
            for (int i = 0; i < 4; i++) a[i]  = Ws[k][ty*4 + i];
            #pragma unroll
            for (int j = 0; j < 4; j++) bb[j] = Xs[k][tx*4 + j];
            #pragma unroll
            for (int i = 0; i < 4; i++)
                #pragma unroll
                for (int j = 0; j < 4; j++)
                    acc[i][j] += a[i] * bb[j];
        }
        __syncthreads();
    }

    #pragma unroll
    for (int i = 0; i < 4; i++) {
        const int o = o0 + ty*4 + i;
        const float bv = bias[o];
        const size_t row = (size_t)b * CCH * NPOS + (size_t)o * NPOS + n0 + tx*4;
        float4 v;
        v.x = acc[i][0] + bv; v.y = acc[i][1] + bv;
        v.z = acc[i][2] + bv; v.w = acc[i][3] + bv;
        if (resid) {
            const float4 r = *(const float4*)&resid[row];
            v.x += r.x; v.y += r.y; v.z += r.z; v.w += r.w;
        }
        *(float4*)&Y[row] = v;
    }
}

// ---------------------------------------------------------------------------
// Flash-style attention, fp32.
// Q,K,V: [B, C, N] channel-major. O[b,c,i] = sum_j softmax_j(Q.K*scale) V[c,j]
// Block: 32 query positions, loop j in tiles of 32. 256 threads.
// grid: (NPOS/32, BATCH)
// ---------------------------------------------------------------------------
__global__ __launch_bounds__(256) void attn_kernel(
    const float* __restrict__ Q, const float* __restrict__ K,
    const float* __restrict__ V, float* __restrict__ O)
{
    const float scale = 0.0625f;            // 256^-0.5
    const int b  = blockIdx.y;
    const int i0 = blockIdx.x * 32;
    const int t  = threadIdx.x;
    const size_t bo = (size_t)b * CCH * NPOS;

    __shared__ float Qs[32][260];   // Qs[q][c], pad 260 keeps float4 align
    __shared__ float Ks[256][32];   // Ks[c][j]
    __shared__ float Vs[256][36];   // Vs[c][j], pad for b128 reads
    __shared__ float Sb[32][36];    // scores / probabilities
    __shared__ float alphaS[32];
    __shared__ float linv[32];

    // load Q tile (coalesced: consecutive t -> consecutive q)
    for (int idx = t; idx < 32 * 256; idx += 256) {
        const int q = idx & 31, c = idx >> 5;
        Qs[q][c] = Q[bo + (size_t)c * NPOS + i0 + q];
    }

    float m = -1e30f, l = 0.f;
    float acc[32];
    #pragma unroll
    for (int q = 0; q < 32; q++) acc[q] = 0.f;

    const int qrow = t & 31;
    const int jg   = t >> 5;     // 0..7 -> 4 j-columns each

    for (int j0 = 0; j0 < NPOS; j0 += 32) {
        // stage K,V tiles
        for (int idx = t; idx < 256 * 32; idx += 256) {
            const int j = idx & 31, c = idx >> 5;
            Ks[c][j] = K[bo + (size_t)c * NPOS + j0 + j];
            Vs[c][j] = V[bo + (size_t)c * NPOS + j0 + j];
        }
        __syncthreads();

        // S[qrow][jg*4 .. +3] = sum_c Q[qrow][c] * K[c][j]
        float4 sacc = make_float4(0.f, 0.f, 0.f, 0.f);
        #pragma unroll 4
        for (int c = 0; c < 256; c += 4) {
            const float4 qv = *(const float4*)&Qs[qrow][c];
            const float* kp = &Ks[c][jg * 4];
            const float4 k0 = *(const float4*)(kp);
            const float4 k1 = *(const float4*)(kp + 32);
            const float4 k2 = *(const float4*)(kp + 64);
            const float4 k3 = *(const float4*)(kp + 96);
            sacc.x += qv.x*k0.x + qv.y*k1.x + qv.z*k2.x + qv.w*k3.x;
            sacc.y += qv.x*k0.y + qv.y*k1.y + qv.z*k2.y + qv.w*k3.y;
            sacc.z += qv.x*k0.z + qv.y*k1.z + qv.z*k2.z + qv.w*k3.z;
            sacc.w += qv.x*k0.w + qv.y*k1.w + qv.z*k2.w + qv.w*k3.w;
        }
        float4 sv;
        sv.x = sacc.x * scale; sv.y = sacc.y * scale;
        sv.z = sacc.z * scale; sv.w = sacc.w * scale;
        *(float4*)&Sb[qrow][jg * 4] = sv;
        __syncthreads();

        // online softmax for rows (threads 0..31 own row state m,l)
        if (t < 32) {
            const int q = t;
            float mx = m;
            #pragma unroll
            for (int j = 0; j < 32; j++) mx = fmaxf(mx, Sb[q][j]);
            const float alpha = __expf(m - mx);
            float ps = 0.f;
            #pragma unroll
            for (int j = 0; j < 32; j++) {
                const float p = __expf(Sb[q][j] - mx);
                Sb[q][j] = p;
                ps += p;
            }
            l = l * alpha + ps;
            m = mx;
            alphaS[q] = alpha;
        }
        __syncthreads();

        // PV: thread owns channel c = t
        float vr[32];
        #pragma unroll
        for (int g2 = 0; g2 < 8; g2++) {
            const float4 vv = *(const float4*)&Vs[t][g2 * 4];
            vr[g2*4 + 0] = vv.x; vr[g2*4 + 1] = vv.y;
            vr[g2*4 + 2] = vv.z; vr[g2*4 + 3] = vv.w;
        }
        #pragma unroll
        for (int q = 0; q < 32; q++) {
            float a = acc[q] * alphaS[q];
            #pragma unroll
            for (int g2 = 0; g2 < 8; g2++) {
                const float4 p = *(const float4*)&Sb[q][g2 * 4];
                a += p.x * vr[g2*4 + 0] + p.y * vr[g2*4 + 1]
                   + p.z * vr[g2*4 + 2] + p.w * vr[g2*4 + 3];
            }
            acc[q] = a;
        }
        __syncthreads();   // before next tile overwrites Ks/Vs/Sb
    }

    if (t < 32) linv[t] = 1.0f / l;
    __syncthreads();

    // O[b, c=t, i0+q]; per-thread contiguous 128B
    #pragma unroll
    for (int qg = 0; qg < 8; qg++) {
        float4 ov;
        ov.x = acc[qg*4 + 0] * linv[qg*4 + 0];
        ov.y = acc[qg*4 + 1] * linv[qg*4 + 1];
        ov.z = acc[qg*4 + 2] * linv[qg*4 + 2];
        ov.w = acc[qg*4 + 3] * linv[qg*4 + 3];
        *(float4*)&O[bo + (size_t)t * NPOS + i0 + qg*4] = ov;
    }
}

// ---------------------------------------------------------------------------
extern "C" void kernel_launch(void* const* d_in, const int* in_sizes, int n_in,
                              void* d_out, int out_size, void* d_ws, size_t ws_size,
                              hipStream_t stream)
{
    const float* x   = (const float*)d_in[0];
    const float* gns = (const float*)d_in[1];
    const float* gnb = (const float*)d_in[2];
    const float* Wq  = (const float*)d_in[3];
    const float* bq  = (const float*)d_in[4];
    const float* Wk  = (const float*)d_in[5];
    const float* bk  = (const float*)d_in[6];
    const float* Wv  = (const float*)d_in[7];
    const float* bv  = (const float*)d_in[8];
    const float* Wf  = (const float*)d_in[9];
    const float* bf  = (const float*)d_in[10];
    float* out = (float*)d_out;
    float* ws  = (float*)d_ws;

    const size_t SZ = (size_t)BATCH * CCH * NPOS;   // 4M floats
    float* xn = ws;            // [B,C,N]; reused as attention output later
    float* Qb = ws + SZ;
    float* Kb = ws + 2 * SZ;
    float* Vb = ws + 3 * SZ;
    float* AO = ws;            // alias xn (xn dead after QKV projections)

    gn_kernel<<<dim3(BATCH * NGRP), 256, 0, stream>>>(x, gns, gnb, xn);

    dim3 gg(NPOS / 64, CCH / 64, BATCH);
    gemm256<<<gg, 256, 0, stream>>>(Wq, xn, bq, nullptr, Qb);
    gemm256<<<gg, 256, 0, stream>>>(Wk, xn, bk, nullptr, Kb);
    gemm256<<<gg, 256, 0, stream>>>(Wv, xn, bv, nullptr, Vb);

    attn_kernel<<<dim3(NPOS / 32, BATCH), 256, 0, stream>>>(Qb, Kb, Vb, AO);

    gemm256<<<gg, 256, 0, stream>>>(Wf, AO, bf, x, out);
}

// Round 3
// 601.397 us; speedup vs baseline: 5.3747x; 5.3747x over previous
//
#include <hip/hip_runtime.h>
#include <hip/hip_bf16.h>

#define BATCH 4
#define CCH   256
#define NPOS  4096
#define NGRP  8
#define CPG   32

typedef __attribute__((ext_vector_type(8))) short bfx8;
typedef __attribute__((ext_vector_type(4))) short bfx4;
typedef __attribute__((ext_vector_type(4))) float f32x4;

__device__ inline short f2bf(float f){
    unsigned u = __builtin_bit_cast(unsigned, f);
    u += 0x7fffu + ((u >> 16) & 1u);
    return (short)(u >> 16);
}

// ---------------------------------------------------------------------------
// GroupNorm: one block per (b,g). fp32 out (channel-major [C][N]).
// ---------------------------------------------------------------------------
__global__ __launch_bounds__(256) void gn_kernel(
    const float* __restrict__ x, const float* __restrict__ gamma,
    const float* __restrict__ beta, float* __restrict__ xn)
{
    const int bg = blockIdx.x;
    const int g  = bg & (NGRP - 1);
    const size_t base = (size_t)bg * CPG * NPOS;
    const int t = threadIdx.x;
    const int M4 = CPG * NPOS / 4;

    const float4* x4 = (const float4*)(x + base);
    float s = 0.f, s2 = 0.f;
    for (int i = t; i < M4; i += 256) {
        float4 v = x4[i];
        s  += v.x + v.y + v.z + v.w;
        s2 += v.x*v.x + v.y*v.y + v.z*v.z + v.w*v.w;
    }
    for (int off = 32; off; off >>= 1) {
        s  += __shfl_down(s,  off);
        s2 += __shfl_down(s2, off);
    }
    __shared__ float rs[4], rs2[4];
    __shared__ float mu_s, rstd_s;
    const int wid = t >> 6;
    if ((t & 63) == 0) { rs[wid] = s; rs2[wid] = s2; }
    __syncthreads();
    if (t == 0) {
        float S  = rs[0] + rs[1] + rs[2] + rs[3];
        float S2 = rs2[0] + rs2[1] + rs2[2] + rs2[3];
        const float inv = 1.0f / (float)(CPG * NPOS);
        float mu  = S * inv;
        float var = S2 * inv - mu * mu;
        mu_s = mu;
        rstd_s = rsqrtf(var + 1e-5f);
    }
    __syncthreads();
    const float mu = mu_s, rstd = rstd_s;
    float4* o4 = (float4*)(xn + base);
    for (int i = t; i < M4; i += 256) {
        const int c = g * CPG + (i >> 10);
        const float ga = gamma[c] * rstd;
        const float be = beta[c] - mu * ga;
        float4 v = x4[i];
        v.x = v.x * ga + be;
        v.y = v.y * ga + be;
        v.z = v.z * ga + be;
        v.w = v.w * ga + be;
        o4[i] = v;
    }
}

// ---------------------------------------------------------------------------
// GEMM: acc[o][n] = sum_c W[o,c] * X[b,c,n]
// MODE 0: fp32 channel-major out + bias + resid
// MODE 1: bf16 position-major out [N][C], (acc+bias)*scale
// MODE 2: bf16 channel-major out [C][N], (acc+bias)*scale
// ---------------------------------------------------------------------------
template<int MODE>
__global__ __launch_bounds__(256) void gemm256(
    const float* __restrict__ W, const float* __restrict__ X,
    const float* __restrict__ bias, const float* __restrict__ resid,
    float* __restrict__ Yf, short* __restrict__ Yb, float scale)
{
    const int b  = blockIdx.z;
    const int n0 = blockIdx.x * 64;
    const int o0 = blockIdx.y * 64;
    const int t  = threadIdx.x;
    const int tx = t & 15, ty = t >> 4;

    __shared__ float Ws[16][68];
    __shared__ float Xs[16][64];

    float acc[4][4];
    #pragma unroll
    for (int i = 0; i < 4; i++)
        #pragma unroll
        for (int j = 0; j < 4; j++) acc[i][j] = 0.f;

    const float* Xb = X + (size_t)b * CCH * NPOS;

    for (int kk = 0; kk < CCH; kk += 16) {
        {
            const int c = t & 15;
            const int r = t >> 4;
            #pragma unroll
            for (int i = 0; i < 4; i++)
                Ws[c][r + i*16] = W[(size_t)(o0 + r + i*16) * CCH + kk + c];
        }
        {
            const int cc = t & 63;
            const int rr = t >> 6;
            #pragma unroll
            for (int i = 0; i < 4; i++)
                Xs[rr + i*4][cc] = Xb[(size_t)(kk + rr + i*4) * NPOS + n0 + cc];
        }
        __syncthreads();
        #pragma unroll
        for (int k = 0; k < 16; k++) {
            float a[4], bb[4];
            #pragma unroll
            for (int i = 0; i < 4; i++) a[i]  = Ws[k][ty*4 + i];
            #pragma unroll
            for (int j = 0; j < 4; j++) bb[j] = Xs[k][tx*4 + j];
            #pragma unroll
            for (int i = 0; i < 4; i++)
                #pragma unroll
                for (int j = 0; j < 4; j++)
                    acc[i][j] += a[i] * bb[j];
        }
        __syncthreads();
    }

    if constexpr (MODE == 0) {
        #pragma unroll
        for (int i = 0; i < 4; i++) {
            const int o = o0 + ty*4 + i;
            const float bv = bias[o];
            const size_t row = (size_t)b * CCH * NPOS + (size_t)o * NPOS + n0 + tx*4;
            float4 v;
            v.x = acc[i][0] + bv; v.y = acc[i][1] + bv;
            v.z = acc[i][2] + bv; v.w = acc[i][3] + bv;
            const float4 r = *(const float4*)&resid[row];
            v.x += r.x; v.y += r.y; v.z += r.z; v.w += r.w;
            *(float4*)&Yf[row] = v;
        }
    } else if constexpr (MODE == 1) {
        short* Yb_b = Yb + (size_t)b * CCH * NPOS;
        float bv[4];
        #pragma unroll
        for (int i = 0; i < 4; i++) bv[i] = bias[o0 + ty*4 + i];
        #pragma unroll
        for (int j = 0; j < 4; j++) {
            const int n = n0 + tx*4 + j;
            bfx4 sv;
            #pragma unroll
            for (int i = 0; i < 4; i++) sv[i] = f2bf((acc[i][j] + bv[i]) * scale);
            *(bfx4*)&Yb_b[(size_t)n * CCH + o0 + ty*4] = sv;
        }
    } else {
        short* Yb_b = Yb + (size_t)b * CCH * NPOS;
        #pragma unroll
        for (int i = 0; i < 4; i++) {
            const int o = o0 + ty*4 + i;
            const float bv = bias[o];
            bfx4 sv;
            #pragma unroll
            for (int j = 0; j < 4; j++) sv[j] = f2bf((acc[i][j] + bv) * scale);
            *(bfx4*)&Yb_b[(size_t)o * NPOS + n0 + tx*4] = sv;
        }
    }
}

// ---------------------------------------------------------------------------
// MFMA flash attention. Q,K bf16 [N][C] position-major (Q pre-scaled), V bf16
// [C][N]. 4 waves x 32 q-rows = QB 128. KVB=32, KV split in 2 halves across
// blockIdx.y. Outputs unnormalized O + per-row m,l for the combine pass.
// grid (32, 2, 4), block 256.
// ---------------------------------------------------------------------------
#define QB  128
#define QW  32
#define KVB 32

__global__ __launch_bounds__(256, 1) void attn_mfma(
    const short* __restrict__ Qt, const short* __restrict__ Kt,
    const short* __restrict__ Vc, float* __restrict__ Op0,
    float* __restrict__ Op1, float* __restrict__ Mp, float* __restrict__ Lp)
{
    const int t = threadIdx.x;
    const int w = t >> 6;
    const int l = t & 63;
    const int lg = l >> 4;
    const int ln = l & 15;
    const int h  = blockIdx.y;
    const int b  = blockIdx.z;

    const size_t bqk = (size_t)b * CCH * NPOS;
    const short* Qg = Qt + bqk;
    const short* Kg = Kt + bqk;
    const short* Vg = Vc + bqk;
    float* Op = h ? Op1 : Op0;

    __shared__ __align__(16) short Ks[KVB * 256];   // [j][d], XOR-swizzled
    __shared__ __align__(16) short Vt[256 * 40];    // [d][j], pad-40 stride
    __shared__ __align__(16) short Ps[4][QW * KVB]; // per-wave [q][j], swizzled

    // Q fragments (held whole loop)
    bfx8 qf[2][8];
    const int qbase = blockIdx.x * QB + w * QW;
    #pragma unroll
    for (int mt = 0; mt < 2; mt++) {
        const size_t row = (size_t)(qbase + mt*16 + ln) * CCH;
        #pragma unroll
        for (int kt = 0; kt < 8; kt++)
            qf[mt][kt] = *(const bfx8*)&Qg[row + kt*32 + lg*8];
    }

    f32x4 acc[2][16];
    #pragma unroll
    for (int mt = 0; mt < 2; mt++)
        #pragma unroll
        for (int dt = 0; dt < 16; dt++)
            acc[mt][dt] = (f32x4){0.f, 0.f, 0.f, 0.f};
    float m_[2][4], l_[2][4];
    #pragma unroll
    for (int mt = 0; mt < 2; mt++)
        #pragma unroll
        for (int r = 0; r < 4; r++) { m_[mt][r] = -1e30f; l_[mt][r] = 0.f; }

    const int j0base = h * (NPOS / 2);

    for (int s = 0; s < (NPOS / 2) / KVB; s++) {
        const int j0 = j0base + s * KVB;
        __syncthreads();
        // stage K tile: 32 rows x 256 d
        #pragma unroll
        for (int i = 0; i < 4; i++) {
            const int idx = t + i * 256;
            const int j  = idx >> 5;
            const int dc = (idx & 31) * 8;
            bfx8 v = *(const bfx8*)&Kg[(size_t)(j0 + j) * CCH + dc];
            *(bfx8*)&Ks[j * 256 + (dc ^ ((j & 7) << 3))] = v;
        }
        // stage V tile: 256 rows x 32 j (pad-40 rows)
        #pragma unroll
        for (int i = 0; i < 4; i++) {
            const int idx = t + i * 256;
            const int d  = idx >> 2;
            const int jc = (idx & 3) * 8;
            bfx8 v = *(const bfx8*)&Vg[(size_t)d * NPOS + j0 + jc];
            *(bfx8*)&Vt[d * 40 + jc] = v;
        }
        __syncthreads();

        // QK^T: S[q][j]
        f32x4 S[2][2];
        #pragma unroll
        for (int jt = 0; jt < 2; jt++) {
            f32x4 s0 = (f32x4){0.f,0.f,0.f,0.f}, s1 = (f32x4){0.f,0.f,0.f,0.f};
            const int j = jt*16 + ln;
            #pragma unroll
            for (int kt = 0; kt < 8; kt++) {
                const bfx8 kf = *(const bfx8*)&Ks[j * 256 + ((kt*32 + lg*8) ^ ((j & 7) << 3))];
                s0 = __builtin_amdgcn_mfma_f32_16x16x32_bf16(qf[0][kt], kf, s0, 0, 0, 0);
                s1 = __builtin_amdgcn_mfma_f32_16x16x32_bf16(qf[1][kt], kf, s1, 0, 0, 0);
            }
            S[0][jt] = s0; S[1][jt] = s1;
        }

        // online softmax (rows live in regs across the 16-lane group)
        #pragma unroll
        for (int mt = 0; mt < 2; mt++) {
            #pragma unroll
            for (int r = 0; r < 4; r++) {
                float mx = fmaxf(S[mt][0][r], S[mt][1][r]);
                mx = fmaxf(mx, __shfl_xor(mx, 1));
                mx = fmaxf(mx, __shfl_xor(mx, 2));
                mx = fmaxf(mx, __shfl_xor(mx, 4));
                mx = fmaxf(mx, __shfl_xor(mx, 8));
                const float mn = fmaxf(m_[mt][r], mx);
                const float al = __expf(m_[mt][r] - mn);
                const float p0 = __expf(S[mt][0][r] - mn);
                const float p1 = __expf(S[mt][1][r] - mn);
                float ps = p0 + p1;
                ps += __shfl_xor(ps, 1);
                ps += __shfl_xor(ps, 2);
                ps += __shfl_xor(ps, 4);
                ps += __shfl_xor(ps, 8);
                l_[mt][r] = l_[mt][r] * al + ps;
                m_[mt][r] = mn;
                #pragma unroll
                for (int dt = 0; dt < 16; dt++) acc[mt][dt][r] *= al;
                const int qrow = mt*16 + lg*4 + r;
                Ps[w][qrow * KVB + ((ln)      ^ ((qrow & 3) << 3))] = f2bf(p0);
                Ps[w][qrow * KVB + ((16 + ln) ^ ((qrow & 3) << 3))] = f2bf(p1);
            }
        }
        asm volatile("s_waitcnt lgkmcnt(0)" ::: "memory");
        __builtin_amdgcn_sched_barrier(0);

        // PV: acc[q][d] += P[q][j] * V[d][j]
        bfx8 pf[2];
        #pragma unroll
        for (int mt = 0; mt < 2; mt++) {
            const int q = mt*16 + ln;
            pf[mt] = *(const bfx8*)&Ps[w][q * KVB + ((lg*8) ^ ((q & 3) << 3))];
        }
        #pragma unroll
        for (int dt = 0; dt < 16; dt++) {
            const int d = dt*16 + ln;
            const bfx8 vf = *(const bfx8*)&Vt[d * 40 + lg*8];
            acc[0][dt] = __builtin_amdgcn_mfma_f32_16x16x32_bf16(pf[0], vf, acc[0][dt], 0, 0, 0);
            acc[1][dt] = __builtin_amdgcn_mfma_f32_16x16x32_bf16(pf[1], vf, acc[1][dt], 0, 0, 0);
        }
    }

    // epilogue: unnormalized O position-major + m,l
    const size_t obase = (size_t)b * NPOS * CCH;
    #pragma unroll
    for (int mt = 0; mt < 2; mt++) {
        #pragma unroll
        for (int r = 0; r < 4; r++) {
            const int q = qbase + mt*16 + lg*4 + r;
            #pragma unroll
            for (int dt = 0; dt < 16; dt++)
                Op[obase + (size_t)q * CCH + dt*16 + ln] = acc[mt][dt][r];
            if (ln == 0) {
                Mp[(size_t)h * BATCH * NPOS + (size_t)b * NPOS + q] = m_[mt][r];
                Lp[(size_t)h * BATCH * NPOS + (size_t)b * NPOS + q] = l_[mt][r];
            }
        }
    }
}

// ---------------------------------------------------------------------------
// Combine two KV-half partials, normalize, transpose to channel-major fp32.
// grid (64, 4), block 256.
// ---------------------------------------------------------------------------
__global__ __launch_bounds__(256) void combine_kernel(
    const float* __restrict__ O0, const float* __restrict__ O1,
    const float* __restrict__ Mp, const float* __restrict__ Lp,
    float* __restrict__ AO)
{
    const int b  = blockIdx.y;
    const int q0 = blockIdx.x * 64;
    const int t  = threadIdx.x;
    __shared__ float s0[64], s1[64];
    __shared__ float T[128][68];
    if (t < 64) {
        const int q = b * NPOS + q0 + t;
        const float m0 = Mp[q], m1 = Mp[BATCH * NPOS + q];
        const float l0 = Lp[q], l1 = Lp[BATCH * NPOS + q];
        const float mm = fmaxf(m0, m1);
        const float e0 = __expf(m0 - mm), e1 = __expf(m1 - mm);
        const float inv = 1.f / (e0 * l0 + e1 * l1);
        s0[t] = e0 * inv; s1[t] = e1 * inv;
    }
    __syncthreads();
    const int r = t >> 2, dq = t & 3;
    const size_t rowbase = ((size_t)b * NPOS + q0 + r) * CCH;
    for (int half = 0; half < 2; half++) {
        const int db = half * 128 + dq * 32;
        const float a0 = s0[r], a1 = s1[r];
        #pragma unroll
        for (int i = 0; i < 8; i++) {
            float4 u = *(const float4*)&O0[rowbase + db + i*4];
            float4 v = *(const float4*)&O1[rowbase + db + i*4];
            T[dq*32 + i*4 + 0][r] = a0*u.x + a1*v.x;
            T[dq*32 + i*4 + 1][r] = a0*u.y + a1*v.y;
            T[dq*32 + i*4 + 2][r] = a0*u.z + a1*v.z;
            T[dq*32 + i*4 + 3][r] = a0*u.w + a1*v.w;
        }
        __syncthreads();
        const int dl = t >> 1, c0 = (t & 1) * 32;
        float* dst = &AO[((size_t)b * CCH + half*128 + dl) * NPOS + q0 + c0];
        #pragma unroll
        for (int i = 0; i < 8; i++)
            *(float4*)&dst[i*4] = *(const float4*)&T[dl][c0 + i*4];
        __syncthreads();
    }
}

// ---------------------------------------------------------------------------
extern "C" void kernel_launch(void* const* d_in, const int* in_sizes, int n_in,
                              void* d_out, int out_size, void* d_ws, size_t ws_size,
                              hipStream_t stream)
{
    const float* x   = (const float*)d_in[0];
    const float* gns = (const float*)d_in[1];
    const float* gnb = (const float*)d_in[2];
    const float* Wq  = (const float*)d_in[3];
    const float* bq  = (const float*)d_in[4];
    const float* Wk  = (const float*)d_in[5];
    const float* bk  = (const float*)d_in[6];
    const float* Wv  = (const float*)d_in[7];
    const float* bv  = (const float*)d_in[8];
    const float* Wf  = (const float*)d_in[9];
    const float* bf  = (const float*)d_in[10];
    float* out = (float*)d_out;
    float* ws  = (float*)d_ws;

    const size_t SZ = (size_t)BATCH * CCH * NPOS;   // 4M elements

    float* xn  = ws;                                 // [0, SZ) fp32
    short* Qt  = (short*)(ws + SZ);                  // [SZ, 1.5SZ) bf16 [B][N][C]
    short* Kt  = (short*)(ws + SZ + SZ/2);           // [1.5SZ, 2SZ) bf16 [B][N][C]
    short* Vc  = (short*)(ws + 2*SZ);                // [2SZ, 2.5SZ) bf16 [B][C][N]
    float* Op1 = ws + 2*SZ + SZ/2;                   // [2.5SZ, 3.5SZ)
    float* Mp  = ws + 3*SZ + SZ/2;                   // 2*B*N floats
    float* Lp  = Mp + 2*BATCH*NPOS;
    float* Op0 = ws;                                 // alias xn (dead after QKV)
    float* AO  = ws + SZ;                            // alias Qt/Kt (dead after attn)

    gn_kernel<<<dim3(BATCH * NGRP), 256, 0, stream>>>(x, gns, gnb, xn);

    dim3 gg(NPOS / 64, CCH / 64, BATCH);
    gemm256<1><<<gg, 256, 0, stream>>>(Wq, xn, bq, nullptr, nullptr, Qt, 0.0625f);
    gemm256<1><<<gg, 256, 0, stream>>>(Wk, xn, bk, nullptr, nullptr, Kt, 1.f);
    gemm256<2><<<gg, 256, 0, stream>>>(Wv, xn, bv, nullptr, nullptr, Vc, 1.f);

    attn_mfma<<<dim3(NPOS / QB, 2, BATCH), 256, 0, stream>>>(Qt, Kt, Vc, Op0, Op1, Mp, Lp);

    combine_kernel<<<dim3(NPOS / 64, BATCH), 256, 0, stream>>>(Op0, Op1, Mp, Lp, AO);

    gemm256<0><<<gg, 256, 0, stream>>>(Wf, AO, bf, x, out, nullptr, 1.f);
}

// Round 5
// 245.931 us; speedup vs baseline: 13.1433x; 2.4454x over previous
//
#include <hip/hip_runtime.h>
#include <hip/hip_bf16.h>

#define BATCH 4
#define CCH   256
#define NPOS  4096
#define NGRP  8
#define CPG   32
#define KVB   32
#define QB    256            // q rows per attn block (8 waves x 32)
#define NSPLIT 4
#define JLEN  (NPOS / NSPLIT)   // 1024
#define NITER (JLEN / KVB)      // 32

typedef __attribute__((ext_vector_type(8))) short bfx8;
typedef __attribute__((ext_vector_type(4))) float f32x4;
typedef __attribute__((ext_vector_type(2))) unsigned int u32x2;
typedef __attribute__((ext_vector_type(4))) unsigned int u32x4;

__device__ __forceinline__ short f2bf(float f){
    unsigned u = __builtin_bit_cast(unsigned, f);
    u += 0x7fffu + ((u >> 16) & 1u);
    return (short)(u >> 16);
}
__device__ __forceinline__ float bf2f(short s){
    unsigned u = ((unsigned)(unsigned short)s) << 16;
    return __builtin_bit_cast(float, u);
}

// ---------------------------------------------------------------------------
// GroupNorm stats: grid (32 bg, 8 parts), 256 thr. Partial sums to psum.
// ---------------------------------------------------------------------------
__global__ __launch_bounds__(256) void gn_stats(
    const float* __restrict__ x, float* __restrict__ psum)
{
    const int bg = blockIdx.x, p = blockIdx.y;
    const size_t base = (size_t)bg * (CPG * NPOS) + (size_t)p * 16384;
    const float4* x4 = (const float4*)(x + base);
    float s = 0.f, s2 = 0.f;
    for (int i = threadIdx.x; i < 4096; i += 256) {
        float4 v = x4[i];
        s  += v.x + v.y + v.z + v.w;
        s2 += v.x*v.x + v.y*v.y + v.z*v.z + v.w*v.w;
    }
    for (int off = 32; off; off >>= 1) {
        s  += __shfl_down(s,  off);
        s2 += __shfl_down(s2, off);
    }
    __shared__ float rs[4], rs2[4];
    const int t = threadIdx.x;
    if ((t & 63) == 0) { rs[t >> 6] = s; rs2[t >> 6] = s2; }
    __syncthreads();
    if (t == 0) {
        psum[(bg*8 + p)*2 + 0] = rs[0] + rs[1] + rs[2] + rs[3];
        psum[(bg*8 + p)*2 + 1] = rs2[0] + rs2[1] + rs2[2] + rs2[3];
    }
}

// ---------------------------------------------------------------------------
// GroupNorm apply + transpose to position-major bf16 [B][N][C].
// grid (32 n-chunks, 32 bg), 256 thr. Chunk = 128 n x 32 c.
// ---------------------------------------------------------------------------
__global__ __launch_bounds__(256) void gn_apply(
    const float* __restrict__ x, const float* __restrict__ gamma,
    const float* __restrict__ beta, const float* __restrict__ psum,
    short* __restrict__ xnb)
{
    const int ch = blockIdx.x, bg = blockIdx.y;
    const int b = bg >> 3, g = bg & 7;
    float S = 0.f, S2 = 0.f;
    #pragma unroll
    for (int p = 0; p < 8; p++) {
        S  += psum[(bg*8 + p)*2 + 0];
        S2 += psum[(bg*8 + p)*2 + 1];
    }
    const float inv = 1.0f / (float)(CPG * NPOS);
    const float mu = S * inv;
    const float rstd = rsqrtf(S2 * inv - mu * mu + 1e-5f);

    __shared__ float T[32][132];
    const int t = threadIdx.x;
    const int c = t >> 3;               // 0..31
    const int gc = g * CPG + c;
    const float ga = gamma[gc] * rstd;
    const float be = beta[gc] - mu * ga;
    const float* xr = &x[((size_t)b * CCH + gc) * NPOS + ch * 128];
    #pragma unroll
    for (int k = 0; k < 4; k++) {
        const int nl = (t & 7) * 16 + k * 4;
        float4 v = *(const float4*)&xr[nl];
        v.x = v.x * ga + be; v.y = v.y * ga + be;
        v.z = v.z * ga + be; v.w = v.w * ga + be;
        *(float4*)&T[c][nl] = v;
    }
    __syncthreads();
    const int n = t >> 1, hf = t & 1;
    short* orow = &xnb[((size_t)b * NPOS + ch * 128 + n) * CCH + g * CPG + hf * 16];
    bfx8 o0, o1;
    #pragma unroll
    for (int e = 0; e < 8; e++) {
        o0[e] = f2bf(T[hf*16 + e][n]);
        o1[e] = f2bf(T[hf*16 + 8 + e][n]);
    }
    *(bfx8*)&orow[0] = o0;
    *(bfx8*)&orow[8] = o1;
}

// ---------------------------------------------------------------------------
// bf16 MFMA GEMM over channels. A = X [B][N][C] bf16 rows, B = W [O][C] fp32
// (cast to bf16 in staging). Block tile 128(n) x 128(o), 4 waves (2x2),
// wave tile 64x64, BK=32. grid (N/128, C/128, B), 256 thr.
// MODE 0: Y bf16 [B][N][C] = (D[n][o] + bias)*scale   (Q with scale, K)
// MODE 1: Y bf16 [B][C][N] = D[o][n] + bias           (V)
// MODE 2: Y fp32 [B][C][N] = D[o][n] + bias + resid   (final)
// ---------------------------------------------------------------------------
template<int MODE>
__global__ __launch_bounds__(256, 2) void gemm_mfma(
    const float* __restrict__ W, const short* __restrict__ Xb,
    const float* __restrict__ bias, const float* __restrict__ resid,
    short* __restrict__ Yb, float* __restrict__ Yf, float scale)
{
    __shared__ short Wl[128 * 32];
    __shared__ short Xl[128 * 32];
    const int t = threadIdx.x, l = t & 63, w = t >> 6;
    const int lg = l >> 4, ln = l & 15;
    const int b = blockIdx.z;
    const int n0 = blockIdx.x * 128, o0 = blockIdx.y * 128;
    const int wo = (w & 1) * 64, wn = (w >> 1) * 64;
    const short* Xg = Xb + ((size_t)b * NPOS + n0) * CCH;

    f32x4 acc[4][4];
    #pragma unroll
    for (int i = 0; i < 4; i++)
        #pragma unroll
        for (int j = 0; j < 4; j++) acc[i][j] = (f32x4){0.f,0.f,0.f,0.f};

    const int srow = t >> 2;
    const int cb   = (t & 3) * 8;

    for (int kk = 0; kk < CCH; kk += 32) {
        bfx8 xst[2], wst[2];
        #pragma unroll
        for (int k = 0; k < 2; k++) {
            const int row = srow + k * 64;
            xst[k] = *(const bfx8*)&Xg[(size_t)row * CCH + kk + cb];
            const float4 wa = *(const float4*)&W[(size_t)(o0 + row) * CCH + kk + cb];
            const float4 wb = *(const float4*)&W[(size_t)(o0 + row) * CCH + kk + cb + 4];
            wst[k] = (bfx8){ f2bf(wa.x), f2bf(wa.y), f2bf(wa.z), f2bf(wa.w),
                             f2bf(wb.x), f2bf(wb.y), f2bf(wb.z), f2bf(wb.w) };
        }
        __syncthreads();
        #pragma unroll
        for (int k = 0; k < 2; k++) {
            const int row = srow + k * 64;
            *(bfx8*)&Xl[row * 32 + cb] = xst[k];
            *(bfx8*)&Wl[row * 32 + cb] = wst[k];
        }
        __syncthreads();

        bfx8 xf[4], wf[4];
        #pragma unroll
        for (int i = 0; i < 4; i++) {
            xf[i] = *(const bfx8*)&Xl[(wn + i*16 + ln) * 32 + lg * 8];
            wf[i] = *(const bfx8*)&Wl[(wo + i*16 + ln) * 32 + lg * 8];
        }
        #pragma unroll
        for (int i = 0; i < 4; i++)
            #pragma unroll
            for (int j = 0; j < 4; j++) {
                if constexpr (MODE == 0)
                    acc[i][j] = __builtin_amdgcn_mfma_f32_16x16x32_bf16(xf[i], wf[j], acc[i][j], 0,0,0);
                else
                    acc[i][j] = __builtin_amdgcn_mfma_f32_16x16x32_bf16(wf[i], xf[j], acc[i][j], 0,0,0);
            }
    }

    if constexpr (MODE == 0) {
        float bv[4];
        #pragma unroll
        for (int j = 0; j < 4; j++) bv[j] = bias[o0 + wo + j*16 + ln];
        #pragma unroll
        for (int i = 0; i < 4; i++)
            #pragma unroll
            for (int r = 0; r < 4; r++) {
                const int n = n0 + wn + i*16 + lg*4 + r;
                short* dst = &Yb[((size_t)b * NPOS + n) * CCH + o0 + wo];
                #pragma unroll
                for (int j = 0; j < 4; j++)
                    dst[j*16 + ln] = f2bf((acc[i][j][r] + bv[j]) * scale);
            }
    } else {
        #pragma unroll
        for (int i = 0; i < 4; i++)
            #pragma unroll
            for (int r = 0; r < 4; r++) {
                const int o = o0 + wo + i*16 + lg*4 + r;
                const float bv = bias[o];
                const size_t base = ((size_t)b * CCH + o) * NPOS + n0 + wn;
                #pragma unroll
                for (int j = 0; j < 4; j++) {
                    if constexpr (MODE == 1)
                        Yb[base + j*16 + ln] = f2bf(acc[i][j][r] + bv);
                    else
                        Yf[base + j*16 + ln] = acc[i][j][r] + bv + resid[base + j*16 + ln];
                }
            }
    }
}

// ---------------------------------------------------------------------------
// MFMA flash attention, swapped QK^T, in-register P, pi-consistent PV.
// Q,K bf16 [B][N][C] (Q pre-scaled). V bf16 [B][C][N].
// grid (NPOS/QB=16, NSPLIT=4, BATCH=4), 512 thr = 8 waves x 32 q-rows.
// Writes normalized bf16 partial O [N][C] + m,l per split.
// ---------------------------------------------------------------------------
#define SOFTMAX_MT(SA, SB, mreg, lreg, accA, paOut) do { \
    float tm_ = fmaxf(fmaxf(fmaxf(SA[0],SA[1]),fmaxf(SA[2],SA[3])), \
                      fmaxf(fmaxf(SB[0],SB[1]),fmaxf(SB[2],SB[3]))); \
    tm_ = fmaxf(tm_, __shfl_xor(tm_, 16)); \
    tm_ = fmaxf(tm_, __shfl_xor(tm_, 32)); \
    if (__any(tm_ > mreg)) { \
        const float mn_ = fmaxf(mreg, tm_); \
        const float al_ = __expf(mreg - mn_); \
        mreg = mn_; lreg *= al_; \
        const f32x4 alv_ = { __shfl(al_, lg*4+0), __shfl(al_, lg*4+1), \
                             __shfl(al_, lg*4+2), __shfl(al_, lg*4+3) }; \
        _Pragma("unroll") \
        for (int dt_ = 0; dt_ < 16; dt_++) accA[dt_] *= alv_; \
    } \
    const float p0_ = __expf(SA[0]-mreg), p1_ = __expf(SA[1]-mreg); \
    const float p2_ = __expf(SA[2]-mreg), p3_ = __expf(SA[3]-mreg); \
    const float p4_ = __expf(SB[0]-mreg), p5_ = __expf(SB[1]-mreg); \
    const float p6_ = __expf(SB[2]-mreg), p7_ = __expf(SB[3]-mreg); \
    float ps_ = ((p0_+p1_)+(p2_+p3_)) + ((p4_+p5_)+(p6_+p7_)); \
    ps_ += __shfl_xor(ps_, 16); ps_ += __shfl_xor(ps_, 32); \
    lreg += ps_; \
    paOut = (bfx8){ f2bf(p0_), f2bf(p1_), f2bf(p2_), f2bf(p3_), \
                    f2bf(p4_), f2bf(p5_), f2bf(p6_), f2bf(p7_) }; \
} while (0)

__global__ __launch_bounds__(512, 2) void attn_mfma(
    const short* __restrict__ Qt, const short* __restrict__ Kt,
    const short* __restrict__ Vc, short* __restrict__ Op0,
    short* __restrict__ Op123, float* __restrict__ Mp, float* __restrict__ Lp)
{
    __shared__ short Ks[32 * 256];     // [j][c], XOR-swizzled, 16 KiB
    __shared__ short Vt[256 * 40];     // [d][j], pad-40 rows, 20 KiB

    const int t = threadIdx.x;
    const int l = t & 63, w = t >> 6;
    const int lg = l >> 4, ln = l & 15;
    const int h = blockIdx.y, b = blockIdx.z;
    const size_t bo = (size_t)b * NPOS * CCH;
    const short* Qg = Qt + bo;
    const short* Kg = Kt + bo;
    const short* Vg = Vc + bo;
    short* Op = (h == 0) ? Op0 : (Op123 + (size_t)(h - 1) * BATCH * NPOS * CCH);

    const int qbase = blockIdx.x * QB + w * 32;

    bfx8 qf0[8], qf1[8];
    #pragma unroll
    for (int kt = 0; kt < 8; kt++) {
        qf0[kt] = *(const bfx8*)&Qg[(size_t)(qbase + ln) * CCH + kt*32 + lg*8];
        qf1[kt] = *(const bfx8*)&Qg[(size_t)(qbase + 16 + ln) * CCH + kt*32 + lg*8];
    }

    f32x4 acc0[16], acc1[16];
    #pragma unroll
    for (int dt = 0; dt < 16; dt++) {
        acc0[dt] = (f32x4){0.f,0.f,0.f,0.f};
        acc1[dt] = (f32x4){0.f,0.f,0.f,0.f};
    }
    float m0 = -1e30f, l0 = 0.f, m1 = -1e30f, l1 = 0.f;
    const int j0base = h * JLEN;

    for (int s = 0; s < NITER; s++) {
        const int j0 = j0base + s * KVB;
        // global loads to regs (issued before the barrier; fly during waits)
        bfx8 kst[2], vst[2];
        int jK[2], cK[2], dV[2], jV[2];
        #pragma unroll
        for (int k = 0; k < 2; k++) {
            const int idx = t + k * 512;
            jK[k] = idx >> 5;          cK[k] = (idx & 31) * 8;
            dV[k] = idx >> 2;          jV[k] = (idx & 3) * 8;
            kst[k] = *(const bfx8*)&Kg[(size_t)(j0 + jK[k]) * CCH + cK[k]];
            vst[k] = *(const bfx8*)&Vg[(size_t)dV[k] * NPOS + j0 + jV[k]];
        }
        __syncthreads();   // all waves done reading previous tile
        #pragma unroll
        for (int k = 0; k < 2; k++) {
            *(bfx8*)&Ks[jK[k] * 256 + (cK[k] ^ ((jK[k] & 7) << 3))] = kst[k];
            *(bfx8*)&Vt[dV[k] * 40 + jV[k]] = vst[k];
        }
        __syncthreads();   // tile staged

        // QK^T (swapped): S[j][q], A = K rows j, B = Q cols q
        f32x4 S00 = (f32x4){0,0,0,0}, S01 = (f32x4){0,0,0,0};
        f32x4 S10 = (f32x4){0,0,0,0}, S11 = (f32x4){0,0,0,0};
        #pragma unroll
        for (int kt = 0; kt < 8; kt++) {
            const int cA = (kt*32 + lg*8) ^ ((ln & 7) << 3);
            const bfx8 kf0 = *(const bfx8*)&Ks[ln * 256 + cA];
            const bfx8 kf1 = *(const bfx8*)&Ks[(16 + ln) * 256 + cA];
            S00 = __builtin_amdgcn_mfma_f32_16x16x32_bf16(kf0, qf0[kt], S00, 0,0,0);
            S01 = __builtin_amdgcn_mfma_f32_16x16x32_bf16(kf1, qf0[kt], S01, 0,0,0);
            S10 = __builtin_amdgcn_mfma_f32_16x16x32_bf16(kf0, qf1[kt], S10, 0,0,0);
            S11 = __builtin_amdgcn_mfma_f32_16x16x32_bf16(kf1, qf1[kt], S11, 0,0,0);
        }

        // online softmax; P packed in-register with pi(lg,e) = lg*4+(e&3)+16*(e>>2)
        bfx8 pa0, pa1;
        SOFTMAX_MT(S00, S01, m0, l0, acc0, pa0);
        SOFTMAX_MT(S10, S11, m1, l1, acc1, pa1);

        // PV: vf built with the SAME pi via two ds_read_b64 from Vt[d][j]
        #pragma unroll
        for (int dt = 0; dt < 16; dt++) {
            const int d = dt*16 + ln;
            const u32x2 v0 = *(const u32x2*)&Vt[d * 40 + lg*4];        // j = lg*4..+3
            const u32x2 v1 = *(const u32x2*)&Vt[d * 40 + 16 + lg*4];   // j = 16+lg*4..+3
            const bfx8 vf = __builtin_bit_cast(bfx8, (u32x4){ v0[0], v0[1], v1[0], v1[1] });
            acc0[dt] = __builtin_amdgcn_mfma_f32_16x16x32_bf16(pa0, vf, acc0[dt], 0,0,0);
            acc1[dt] = __builtin_amdgcn_mfma_f32_16x16x32_bf16(pa1, vf, acc1[dt], 0,0,0);
        }
    }

    // epilogue: normalize, direct bf16 stores (no LDS)
    {
        const float inv0 = 1.0f / l0;
        const f32x4 lv = { __shfl(inv0, lg*4+0), __shfl(inv0, lg*4+1),
                           __shfl(inv0, lg*4+2), __shfl(inv0, lg*4+3) };
        #pragma unroll
        for (int dt = 0; dt < 16; dt++) {
            const f32x4 o = acc0[dt] * lv;
            const int d = dt*16 + ln;
            #pragma unroll
            for (int r = 0; r < 4; r++)
                Op[((size_t)b * NPOS + qbase + lg*4 + r) * CCH + d] = f2bf(o[r]);
        }
        if (lg == 0) {
            Mp[((size_t)h * BATCH + b) * NPOS + qbase + ln] = m0;
            Lp[((size_t)h * BATCH + b) * NPOS + qbase + ln] = l0;
        }
    }
    {
        const float inv1 = 1.0f / l1;
        const f32x4 lv = { __shfl(inv1, lg*4+0), __shfl(inv1, lg*4+1),
                           __shfl(inv1, lg*4+2), __shfl(inv1, lg*4+3) };
        #pragma unroll
        for (int dt = 0; dt < 16; dt++) {
            const f32x4 o = acc1[dt] * lv;
            const int d = dt*16 + ln;
            #pragma unroll
            for (int r = 0; r < 4; r++)
                Op[((size_t)b * NPOS + qbase + 16 + lg*4 + r) * CCH + d] = f2bf(o[r]);
        }
        if (lg == 0) {
            Mp[((size_t)h * BATCH + b) * NPOS + qbase + 16 + ln] = m1;
            Lp[((size_t)h * BATCH + b) * NPOS + qbase + 16 + ln] = l1;
        }
    }
}

// ---------------------------------------------------------------------------
// Combine 4 normalized split-partials -> AO bf16 [B][N][C] (elementwise).
// grid (NPOS/64, BATCH), 256 thr.
// ---------------------------------------------------------------------------
__global__ __launch_bounds__(256) void combine4(
    const short* __restrict__ Op0, const short* __restrict__ Op123,
    const float* __restrict__ Mp, const float* __restrict__ Lp,
    short* __restrict__ AO)
{
    const int b  = blockIdx.y;
    const int q0 = blockIdx.x * 64;
    const int t  = threadIdx.x;
    __shared__ float wgt[4][64];
    if (t < 64) {
        const size_t qi = (size_t)b * NPOS + q0 + t;
        float mm[4], ll[4];
        #pragma unroll
        for (int hh = 0; hh < 4; hh++) {
            mm[hh] = Mp[(size_t)hh * BATCH * NPOS + qi];
            ll[hh] = Lp[(size_t)hh * BATCH * NPOS + qi];
        }
        const float M = fmaxf(fmaxf(mm[0], mm[1]), fmaxf(mm[2], mm[3]));
        float e[4], sum = 0.f;
        #pragma unroll
        for (int hh = 0; hh < 4; hh++) { e[hh] = __expf(mm[hh] - M) * ll[hh]; sum += e[hh]; }
        const float invs = 1.0f / sum;
        #pragma unroll
        for (int hh = 0; hh < 4; hh++) wgt[hh][t] = e[hh] * invs;
    }
    __syncthreads();
    const size_t hs = (size_t)BATCH * NPOS * CCH;
    #pragma unroll
    for (int i = 0; i < 8; i++) {
        const int flat = i * 256 + t;
        const int q = flat >> 5;
        const int cb = (flat & 31) * 8;
        const size_t row = ((size_t)b * NPOS + q0 + q) * CCH + cb;
        const float w0 = wgt[0][q], w1 = wgt[1][q], w2 = wgt[2][q], w3 = wgt[3][q];
        const bfx8 a0 = *(const bfx8*)&Op0[row];
        const bfx8 a1 = *(const bfx8*)&Op123[row];
        const bfx8 a2 = *(const bfx8*)&Op123[hs + row];
        const bfx8 a3 = *(const bfx8*)&Op123[2*hs + row];
        bfx8 ov;
        #pragma unroll
        for (int e = 0; e < 8; e++)
            ov[e] = f2bf(w0*bf2f(a0[e]) + w1*bf2f(a1[e]) + w2*bf2f(a2[e]) + w3*bf2f(a3[e]));
        *(bfx8*)&AO[row] = ov;
    }
}

// ---------------------------------------------------------------------------
extern "C" void kernel_launch(void* const* d_in, const int* in_sizes, int n_in,
                              void* d_out, int out_size, void* d_ws, size_t ws_size,
                              hipStream_t stream)
{
    const float* x   = (const float*)d_in[0];
    const float* gns = (const float*)d_in[1];
    const float* gnb = (const float*)d_in[2];
    const float* Wq  = (const float*)d_in[3];
    const float* bq  = (const float*)d_in[4];
    const float* Wk  = (const float*)d_in[5];
    const float* bk  = (const float*)d_in[6];
    const float* Wv  = (const float*)d_in[7];
    const float* bv  = (const float*)d_in[8];
    const float* Wf  = (const float*)d_in[9];
    const float* bf  = (const float*)d_in[10];
    float* out = (float*)d_out;
    char* wsb  = (char*)d_ws;

    // workspace map (<= 56.5 MB; proven-safe envelope)
    short* xnb   = (short*)(wsb);                    // [0, 8M)  bf16 [B][N][C]
    short* Op0   = (short*)(wsb);                    // alias (xnb dead post-QKV)
    short* Qt    = (short*)(wsb + (8  << 20));       // [8, 16M)
    short* Kt    = (short*)(wsb + (16 << 20));       // [16, 24M)
    short* Vc    = (short*)(wsb + (24 << 20));       // [24, 32M) bf16 [B][C][N]
    short* Op123 = (short*)(wsb + (32 << 20));       // [32, 56M) 3 partials
    float* Mp    = (float*)(wsb + (56 << 20));       // 256 KB
    float* Lp    = Mp + (size_t)NSPLIT * BATCH * NPOS;
    float* psum  = Lp + (size_t)NSPLIT * BATCH * NPOS;  // 2 KB
    short* AO    = Qt;                               // alias (Qt dead post-attn)

    gn_stats<<<dim3(BATCH * NGRP, 8), 256, 0, stream>>>(x, psum);
    gn_apply<<<dim3(NPOS / 128, BATCH * NGRP), 256, 0, stream>>>(x, gns, gnb, psum, xnb);

    dim3 gg(NPOS / 128, CCH / 128, BATCH);
    gemm_mfma<0><<<gg, 256, 0, stream>>>(Wq, xnb, bq, nullptr, Qt, nullptr, 0.0625f);
    gemm_mfma<0><<<gg, 256, 0, stream>>>(Wk, xnb, bk, nullptr, Kt, nullptr, 1.f);
    gemm_mfma<1><<<gg, 256, 0, stream>>>(Wv, xnb, bv, nullptr, Vc, nullptr, 1.f);

    attn_mfma<<<dim3(NPOS / QB, NSPLIT, BATCH), 512, 0, stream>>>(
        Qt, Kt, Vc, Op0, Op123, Mp, Lp);

    combine4<<<dim3(NPOS / 64, BATCH), 256, 0, stream>>>(Op0, Op123, Mp, Lp, AO);

    gemm_mfma<2><<<gg, 256, 0, stream>>>(Wf, AO, bf, x, nullptr, out, 1.f);
}